// Round 17
// baseline (319.883 us; speedup 1.0000x reference)
//
#include <hip/hip_runtime.h>
#include <float.h>
#include <math.h>
#include <stdint.h>

#define M_ROWS 32768
#define K_CODES 8192
#define DDIM 256
#define BM 64
#define BN 64
#define NTILES (K_CODES / BN)   // 128
#define DELTA 0.009f
#define CAP 16
#define FLAGBIT 0x10000

typedef __attribute__((ext_vector_type(8))) short short8;
typedef __attribute__((ext_vector_type(4))) float f32x4;

__device__ inline unsigned short f2bf(float f) {
    unsigned u = __float_as_uint(f);
    return (unsigned short)((u + 0x7fffu + ((u >> 16) & 1u)) >> 16);
}
__device__ inline unsigned fkey(float f) {
    unsigned u = __float_as_uint(f);
    return u ^ ((unsigned)((int)u >> 31) | 0x80000000u);
}
__device__ inline float fkey_inv(unsigned k) {
    unsigned u = (k & 0x80000000u) ? (k ^ 0x80000000u) : ~k;
    return __uint_as_float(u);
}

#define GLOAD16(gsrc, ldst)                                                     \
    __builtin_amdgcn_global_load_lds(                                           \
        (const __attribute__((address_space(1))) void*)(gsrc),                  \
        (__attribute__((address_space(3))) void*)(ldst), 16, 0, 0)

// ---------------- kernel 1: normalize E -> En (fp32) + En_b (bf16) ----------------
__global__ __launch_bounds__(256) void k_norm_E(const float* __restrict__ E,
                                                float* __restrict__ En,
                                                unsigned short* __restrict__ En_b) {
    int wid  = threadIdx.x >> 6;
    int lane = threadIdx.x & 63;
    int row  = blockIdx.x * 4 + wid;
    const float* e = E + (size_t)row * DDIM;
    float v[4];
    float ssq = 0.f;
#pragma unroll
    for (int p = 0; p < 4; ++p) { v[p] = e[lane + 64 * p]; ssq += v[p] * v[p]; }
#pragma unroll
    for (int off = 32; off >= 1; off >>= 1) ssq += __shfl_xor(ssq, off);
    float inv = 1.f / fmaxf(sqrtf(ssq), 1e-8f);
    float* o = En + (size_t)row * DDIM;
    unsigned short* ob = En_b + (size_t)row * DDIM;
#pragma unroll
    for (int p = 0; p < 4; ++p) {
        float nv = v[p] * inv;
        o[lane + 64 * p]  = nv;
        ob[lane + 64 * p] = f2bf(nv);
    }
}

// ---------------- kernel 2: single-pass top-2 filter, barrier-free wave pipeline --
// Structure = R15/R16 (proven: 240us). ONE change: LDS shrunk to EXACTLY 64 KB
// by unioning the post-loop aux arrays (rowmaxKey/cnt/list, 4.6KB) into the
// B-staging buffer space (disjoint lifetimes: Bw only live during the tile
// loop, aux only after). Hypothesis from R11-R16 correlation: the scheduler's
// usable LDS pool is ~128KB/CU, so 70144B blocked the 2nd co-resident block
// (occupancy pinned 11.4%); 65536B x 2 = 128KB fits -> two de-phased blocks
// overlap MFMA/VALU/LDS pipes (m114). VGPR 160 fits 8 waves/CU (m69 steps).
__global__ __attribute__((amdgpu_flat_work_group_size(256, 256),
                          amdgpu_waves_per_eu(1, 2)))
void k_cand(
    const float* __restrict__ z,
    const unsigned short* __restrict__ En_b,
    unsigned char* __restrict__ cand_cnt,
    int* __restrict__ cand_k) {

    __shared__ __attribute__((aligned(16))) char smem[65536];   // 64 KB total
    // loop phase: per-wave double buffers  smem[wid*16KB + buf*8KB]
    // post-loop:  aux arrays (disjoint lifetime)
    unsigned* rowmaxKey = (unsigned*)smem;                      // 256 B
    int*      cnt       = (int*)(smem + 256);                   // 256 B
    int*      list      = (int*)(smem + 512);                   // BM*CAP*4 = 4 KB

    const int tid  = threadIdx.x;
    const int lane = tid & 63;
    const int wid  = tid >> 6;      // col-group 0..3
    const int lo   = lane & 15;
    const int hi   = lane >> 4;
    const int m0   = blockIdx.x * BM;

    const char* eb = (const char*)En_b;
    char* b0 = smem + wid * 16384;
    char* b1 = smem + wid * 16384 + 8192;

    // precomputed per-lane stage source offsets (addr = tilebase + sofs[i])
    int sofs[8];
#pragma unroll
    for (int i = 0; i < 8; ++i) {
        int G   = i * 64 + lane;            // granule 0..511 in slice
        int row = G >> 5;                   // 0..15 (code within slice)
        int g   = (G & 31) ^ (row & 7);     // pre-swizzled 16B granule
        sofs[i] = (wid * 16 + row) * 512 + g * 16;
    }

    auto stage = [&](int ktile, char* bufp) {
        const char* tb = eb + (size_t)ktile * (BN * 512);
#pragma unroll
        for (int i = 0; i < 8; ++i)
            GLOAD16(tb + sofs[i], bufp + i * 1024);
    };

    stage(0, b0);
    stage(1, b1);

    // ---- A fragments: z fp32 -> normalize in-register -> bf16 ----
    short8 af[4][8];
#pragma unroll
    for (int mi = 0; mi < 4; ++mi) {
        const float* zr = z + (size_t)(m0 + mi * 16 + lo) * DDIM;
        float4 v[16];
        float ssq = 0.f;
#pragma unroll
        for (int ks = 0; ks < 8; ++ks) {
            int e0 = (ks * 4 + hi) * 8;
            v[2 * ks]     = *(const float4*)&zr[e0];
            v[2 * ks + 1] = *(const float4*)&zr[e0 + 4];
            float4 a = v[2 * ks], b = v[2 * ks + 1];
            ssq += a.x * a.x + a.y * a.y + a.z * a.z + a.w * a.w;
            ssq += b.x * b.x + b.y * b.y + b.z * b.z + b.w * b.w;
        }
        ssq += __shfl_xor(ssq, 16);
        ssq += __shfl_xor(ssq, 32);
        float inv = 1.f / fmaxf(sqrtf(ssq), 1e-8f);
#pragma unroll
        for (int ks = 0; ks < 8; ++ks) {
            float4 a = v[2 * ks], b = v[2 * ks + 1];
            short8 s8;
            s8[0] = (short)f2bf(a.x * inv); s8[1] = (short)f2bf(a.y * inv);
            s8[2] = (short)f2bf(a.z * inv); s8[3] = (short)f2bf(a.w * inv);
            s8[4] = (short)f2bf(b.x * inv); s8[5] = (short)f2bf(b.y * inv);
            s8[6] = (short)f2bf(b.z * inv); s8[7] = (short)f2bf(b.w * inv);
            af[mi][ks] = s8;
        }
    }

    // per-slot stream state (slot s = mi*4+r; row = mi*16 + hi*4 + r)
    float v1[16], v2[16];
    int   k1[16];
#pragma unroll
    for (int s = 0; s < 16; ++s) { v1[s] = -FLT_MAX; v2[s] = -FLT_MAX; k1[s] = 0; }

    __syncthreads();   // prologue staging ordered before loop (one-time)

    const int bswz = lo & 7;

    for (int t = 0; t < NTILES; ++t) {
        if (t < NTILES - 1) asm volatile("s_waitcnt vmcnt(8)" ::: "memory");
        else                asm volatile("s_waitcnt vmcnt(0)" ::: "memory");
        __builtin_amdgcn_sched_barrier(0);

        const unsigned short* Bc = (const unsigned short*)((t & 1) ? b1 : b0);
        f32x4 acc[4];
#pragma unroll
        for (int mi = 0; mi < 4; ++mi) acc[mi] = (f32x4){0.f, 0.f, 0.f, 0.f};
#pragma unroll
        for (int ks = 0; ks < 8; ++ks) {
            short8 bf = *(const short8*)&Bc[lo * 256 + (((ks * 4 + hi) ^ bswz)) * 8];
#pragma unroll
            for (int mi = 0; mi < 4; ++mi)
                acc[mi] = __builtin_amdgcn_mfma_f32_16x16x32_bf16(af[mi][ks], bf, acc[mi], 0, 0, 0);
        }

        const int kv = t * BN + wid * 16 + lo;
#pragma unroll
        for (int mi = 0; mi < 4; ++mi)
#pragma unroll
            for (int r = 0; r < 4; ++r) {
                int s = mi * 4 + r;
                float v = acc[mi][r];
                v2[s] = fmaxf(v2[s], fminf(v1[s], v));    // streaming 2nd max
                k1[s] = (v > v1[s]) ? kv : k1[s];
                v1[s] = fmaxf(v1[s], v);
            }

        if (t + 2 < NTILES) {
            // ds_reads of this tile complete before overwriting the buffer
            asm volatile("s_waitcnt lgkmcnt(0)" ::: "memory");
            __builtin_amdgcn_sched_barrier(0);
            stage(t + 2, (t & 1) ? b1 : b0);
        }
    }

    // ---- loop done: vmcnt drained (last iter waits vmcnt(0)); LDS reusable ----
    __syncthreads();                       // all waves finished with Bw region
    if (tid < BM) { cnt[tid] = 0; rowmaxKey[tid] = 0u; }
    __syncthreads();                       // aux init visible

    // ---- exact bf16 row max: reduce v1 over 16 lo-lanes, cross-wave via LDS ----
#pragma unroll
    for (int s = 0; s < 16; ++s) {
        float w = v1[s];
        w = fmaxf(w, __shfl_xor(w, 1));
        w = fmaxf(w, __shfl_xor(w, 2));
        w = fmaxf(w, __shfl_xor(w, 4));
        w = fmaxf(w, __shfl_xor(w, 8));
        if (lo == 0) {
            int row = (s >> 2) * 16 + hi * 4 + (s & 3);
            atomicMax(&rowmaxKey[row], fkey(w));
        }
    }
    __syncthreads();

    // ---- emit candidates + flag entries ----
#pragma unroll
    for (int s = 0; s < 16; ++s) {
        int row = (s >> 2) * 16 + hi * 4 + (s & 3);
        float thr = fkey_inv(rowmaxKey[row]) - DELTA;
        if (v1[s] >= thr) {
            int pos = atomicAdd(&cnt[row], 1);
            if (pos < CAP) list[row * CAP + pos] = k1[s];
        }
        if (v2[s] >= thr) {
            int pos = atomicAdd(&cnt[row], 1);
            if (pos < CAP) list[row * CAP + pos] = FLAGBIT | (wid * 16 + lo);
        }
    }
    __syncthreads();

    if (tid < BM) {
        int c = cnt[tid];
        cand_cnt[m0 + tid] = (unsigned char)(c > CAP ? 255 : c);
        int n = c < CAP ? c : CAP;
        for (int j = 0; j < n; ++j) cand_k[(size_t)(m0 + tid) * CAP + j] = list[tid * CAP + j];
    }
}

// ---------------- kernel 3: rescore (incl. stream rescans) + outputs ----------------
__global__ __launch_bounds__(256) void k_final(
    const float* __restrict__ z,
    const float* __restrict__ E,
    const float* __restrict__ En,
    const unsigned char* __restrict__ cand_cnt,
    const int* __restrict__ cand_k,
    float* __restrict__ out,
    float* __restrict__ rowloss) {

    __shared__ float zl[4][256];
    int wid  = threadIdx.x >> 6;
    int lane = threadIdx.x & 63;
    int m    = blockIdx.x * 4 + wid;

    const float* zr = z + (size_t)m * DDIM;
    const float4 zz = *(const float4*)&zr[lane * 4];
    *(float4*)&zl[wid][lane * 4] = zz;          // full z row for stream rescans
    asm volatile("s_waitcnt lgkmcnt(0)" ::: "memory");

    float bv = -FLT_MAX;
    int   bk = 0x7fffffff;

    // rescan one column-stream (codes k ≡ cb mod 64), 2 codes/lane, exact fp32
    auto rescan = [&](int cb) {
#pragma unroll
        for (int j = 0; j < 2; ++j) {
            int k = cb + (lane * 2 + j) * 64;
            const float4* er = (const float4*)&En[(size_t)k * DDIM];
            float s0 = 0.f, s1 = 0.f, s2 = 0.f, s3 = 0.f;
#pragma unroll 16
            for (int d4 = 0; d4 < 64; ++d4) {
                float4 e  = er[d4];
                float4 zd = *(const float4*)&zl[wid][d4 * 4];
                s0 += zd.x * e.x; s1 += zd.y * e.y;
                s2 += zd.z * e.z; s3 += zd.w * e.w;
            }
            float s = (s0 + s1) + (s2 + s3);
            if (s > bv || (s == bv && k < bk)) { bv = s; bk = k; }
        }
    };

    int c = cand_cnt[m];
    if (c != 255) {
        for (int j = 0; j < c; ++j) {
            int e = cand_k[(size_t)m * CAP + j];
            if (e < FLAGBIT) {
                const float4 ee = *(const float4*)&En[(size_t)e * DDIM + lane * 4];
                float s = zz.x * ee.x + zz.y * ee.y + zz.z * ee.z + zz.w * ee.w;
#pragma unroll
                for (int off = 1; off < 64; off <<= 1) s += __shfl_xor(s, off);
                if (s > bv || (s == bv && e < bk)) { bv = s; bk = e; }
            } else {
                rescan(e & 63);
            }
        }
    } else {
        for (int cb = 0; cb < 64; ++cb) rescan(cb);   // overflow: full exact scan
    }
    // final argmax reduce across lanes (value, min-k tie)
#pragma unroll
    for (int off = 1; off < 64; off <<= 1) {
        float ov = __shfl_xor(bv, off);
        int   ok = __shfl_xor(bk, off);
        if (ov > bv || (ov == bv && ok < bk)) { bv = ov; bk = ok; }
    }
    const int idx = bk;

    // ---- gather + straight-through + per-row loss ----
    const float* er = E + (size_t)idx * DDIM;
    float zv[4], ev[4];
    float sz = 0.f, se = 0.f;
#pragma unroll
    for (int p = 0; p < 4; ++p) {
        zv[p] = zr[lane + 64 * p]; sz += zv[p] * zv[p];
        ev[p] = er[lane + 64 * p]; se += ev[p] * ev[p];
    }
#pragma unroll
    for (int off = 32; off >= 1; off >>= 1) {
        sz += __shfl_xor(sz, off);
        se += __shfl_xor(se, off);
    }
    float nz = fmaxf(sqrtf(sz), 1e-8f);
    float ne = fmaxf(sqrtf(se), 1e-8f);

    float rs = 0.f;
    float* zq = out + 1 + (size_t)m * DDIM;
#pragma unroll
    for (int p = 0; p < 4; ++p) {
        float zn = zv[p] / nz;
        float en = ev[p] / ne;
        float d  = en - zn;
        rs += d * d;
        zq[lane + 64 * p] = zv[p] + (ev[p] - zv[p]);
    }
#pragma unroll
    for (int off = 32; off >= 1; off >>= 1) rs += __shfl_xor(rs, off);

    if (lane == 0) {
        rowloss[m] = rs;
        out[1 + (size_t)M_ROWS * DDIM + m] = (float)idx;
    }
}

// ---------------- kernel 4: deterministic loss reduction ----------------
__global__ __launch_bounds__(256) void k_loss(const float* __restrict__ rowloss,
                                              float* __restrict__ out) {
    __shared__ double sm[256];
    double s = 0.0;
    for (int i = threadIdx.x; i < M_ROWS; i += 256) s += (double)rowloss[i];
    sm[threadIdx.x] = s;
    __syncthreads();
    for (int st = 128; st > 0; st >>= 1) {
        if (threadIdx.x < st) sm[threadIdx.x] += sm[threadIdx.x + st];
        __syncthreads();
    }
    if (threadIdx.x == 0) {
        float c = (float)(sm[0] / (double)((size_t)M_ROWS * DDIM));
        out[0] = c + 0.05f * c;
    }
}

extern "C" void kernel_launch(void* const* d_in, const int* in_sizes, int n_in,
                              void* d_out, int out_size, void* d_ws, size_t ws_size,
                              hipStream_t stream) {
    const float* z = (const float*)d_in[0];
    const float* E = (const float*)d_in[1];
    float* out = (float*)d_out;

    char* ws = (char*)d_ws;
    size_t off = 0;
    float*          En       = (float*)(ws + off);          off += (size_t)K_CODES * DDIM * 4;  // 8 MB
    unsigned short* En_b     = (unsigned short*)(ws + off); off += (size_t)K_CODES * DDIM * 2;  // 4 MB
    int*            cand_k   = (int*)(ws + off);            off += (size_t)M_ROWS * CAP * 4;    // 2 MB
    unsigned char*  cand_cnt = (unsigned char*)(ws + off);  off += (size_t)M_ROWS;              // 32 KB
    float*          rowloss  = (float*)(ws + off);

    k_norm_E<<<K_CODES / 4, 256, 0, stream>>>(E, En, En_b);
    k_cand<<<M_ROWS / BM, 256, 0, stream>>>(z, En_b, cand_cnt, cand_k);
    k_final<<<M_ROWS / 4, 256, 0, stream>>>(z, E, En, cand_cnt, cand_k, out, rowloss);
    k_loss<<<1, 256, 0, stream>>>(rowloss, out);
}

// Round 18
// 299.639 us; speedup vs baseline: 1.0676x; 1.0676x over previous
//
#include <hip/hip_runtime.h>
#include <float.h>
#include <math.h>
#include <stdint.h>

#define M_ROWS 32768
#define K_CODES 8192
#define DDIM 256
#define BM 64
#define BN 64
#define NTILES (K_CODES / BN)   // 128
#define DELTA 0.009f
#define CAP 16
#define FLAGBIT 0x10000

typedef __attribute__((ext_vector_type(8))) short short8;
typedef __attribute__((ext_vector_type(4))) float f32x4;

__device__ inline unsigned short f2bf(float f) {
    unsigned u = __float_as_uint(f);
    return (unsigned short)((u + 0x7fffu + ((u >> 16) & 1u)) >> 16);
}
__device__ inline unsigned fkey(float f) {
    unsigned u = __float_as_uint(f);
    return u ^ ((unsigned)((int)u >> 31) | 0x80000000u);
}
__device__ inline float fkey_inv(unsigned k) {
    unsigned u = (k & 0x80000000u) ? (k ^ 0x80000000u) : ~k;
    return __uint_as_float(u);
}

#define GLOAD16(gsrc, ldst)                                                     \
    __builtin_amdgcn_global_load_lds(                                           \
        (const __attribute__((address_space(1))) void*)(gsrc),                  \
        (__attribute__((address_space(3))) void*)(ldst), 16, 0, 0)

// ---------------- kernel 1: normalize E -> En (fp32) + En_b (bf16) ----------------
__global__ __launch_bounds__(256) void k_norm_E(const float* __restrict__ E,
                                                float* __restrict__ En,
                                                unsigned short* __restrict__ En_b) {
    int wid  = threadIdx.x >> 6;
    int lane = threadIdx.x & 63;
    int row  = blockIdx.x * 4 + wid;
    const float* e = E + (size_t)row * DDIM;
    float v[4];
    float ssq = 0.f;
#pragma unroll
    for (int p = 0; p < 4; ++p) { v[p] = e[lane + 64 * p]; ssq += v[p] * v[p]; }
#pragma unroll
    for (int off = 32; off >= 1; off >>= 1) ssq += __shfl_xor(ssq, off);
    float inv = 1.f / fmaxf(sqrtf(ssq), 1e-8f);
    float* o = En + (size_t)row * DDIM;
    unsigned short* ob = En_b + (size_t)row * DDIM;
#pragma unroll
    for (int p = 0; p < 4; ++p) {
        float nv = v[p] * inv;
        o[lane + 64 * p]  = nv;
        ob[lane + 64 * p] = f2bf(nv);
    }
}

// ---------------- kernel 2: single-pass top-2 filter, barrier-free wave pipeline --
// Structure = R17 (proven 239us). Occupancy fix, theory from R11-R17 evidence:
// gfx950 unified RF = 512 regs/SIMD, 256 arch-VGPR cap/wave; VGPR_Count reports
// only the VGPR half. At (256,1) the allocator used VGPR(160)+AGPR > 256 total
// -> 1 wave/SIMD pinned (occupancy 11.4% in R12-R17 regardless of LDS) and
// accvgpr juggling inflated VALUBusy to 43%. (256,2) forces total<=256
// (af[4][8] -> 128 AGPR, rest -> 128 VGPR; R11 PROVED 2 blocks co-schedule at
// this config). R11's failure was the 64-reg v[16] setup transient overflowing
// the VGPR half into scratch (36MB) -- fixed here by TWO-PASS z setup (ssq pass
// + reload-and-convert pass, 8-reg transient; asm launder prevents load CSE).
__global__ __launch_bounds__(256, 2) void k_cand(
    const float* __restrict__ z,
    const unsigned short* __restrict__ En_b,
    unsigned char* __restrict__ cand_cnt,
    int* __restrict__ cand_k) {

    __shared__ __attribute__((aligned(16))) char smem[65536];   // 64 KB total
    // loop phase: per-wave double buffers  smem[wid*16KB + buf*8KB]
    // post-loop:  aux arrays (disjoint lifetime)
    unsigned* rowmaxKey = (unsigned*)smem;                      // 256 B
    int*      cnt       = (int*)(smem + 256);                   // 256 B
    int*      list      = (int*)(smem + 512);                   // BM*CAP*4 = 4 KB

    const int tid  = threadIdx.x;
    const int lane = tid & 63;
    const int wid  = tid >> 6;      // col-group 0..3
    const int lo   = lane & 15;
    const int hi   = lane >> 4;
    const int m0   = blockIdx.x * BM;

    const char* eb = (const char*)En_b;
    char* b0 = smem + wid * 16384;
    char* b1 = smem + wid * 16384 + 8192;

    // precomputed per-lane stage source offsets (addr = tilebase + sofs[i])
    int sofs[8];
#pragma unroll
    for (int i = 0; i < 8; ++i) {
        int G   = i * 64 + lane;            // granule 0..511 in slice
        int row = G >> 5;                   // 0..15 (code within slice)
        int g   = (G & 31) ^ (row & 7);     // pre-swizzled 16B granule
        sofs[i] = (wid * 16 + row) * 512 + g * 16;
    }

    auto stage = [&](int ktile, char* bufp) {
        const char* tb = eb + (size_t)ktile * (BN * 512);
#pragma unroll
        for (int i = 0; i < 8; ++i)
            GLOAD16(tb + sofs[i], bufp + i * 1024);
    };

    stage(0, b0);
    stage(1, b1);

    // ---- A fragments: TWO-PASS z setup (8-reg transient, no spill) ----
    short8 af[4][8];
#pragma unroll
    for (int mi = 0; mi < 4; ++mi) {
        const float* zr = z + (size_t)(m0 + mi * 16 + lo) * DDIM;
        // pass 1: sum of squares only
        float ssq = 0.f;
#pragma unroll
        for (int ks = 0; ks < 8; ++ks) {
            int e0 = (ks * 4 + hi) * 8;
            float4 a = *(const float4*)&zr[e0];
            float4 b = *(const float4*)&zr[e0 + 4];
            ssq += a.x * a.x + a.y * a.y + a.z * a.z + a.w * a.w;
            ssq += b.x * b.x + b.y * b.y + b.z * b.z + b.w * b.w;
        }
        // 4 hi-lanes hold disjoint 64-element subsets of the row
        ssq += __shfl_xor(ssq, 16);
        ssq += __shfl_xor(ssq, 32);
        float inv = 1.f / fmaxf(sqrtf(ssq), 1e-8f);
        // pass 2: reload (L1/L2-hot) through laundered pointer -> no CSE with pass 1
        const float* zr2 = zr;
        asm volatile("" : "+v"(zr2));
#pragma unroll
        for (int ks = 0; ks < 8; ++ks) {
            int e0 = (ks * 4 + hi) * 8;
            float4 a = *(const float4*)&zr2[e0];
            float4 b = *(const float4*)&zr2[e0 + 4];
            short8 s8;
            s8[0] = (short)f2bf(a.x * inv); s8[1] = (short)f2bf(a.y * inv);
            s8[2] = (short)f2bf(a.z * inv); s8[3] = (short)f2bf(a.w * inv);
            s8[4] = (short)f2bf(b.x * inv); s8[5] = (short)f2bf(b.y * inv);
            s8[6] = (short)f2bf(b.z * inv); s8[7] = (short)f2bf(b.w * inv);
            af[mi][ks] = s8;
        }
    }

    // per-slot stream state (slot s = mi*4+r; row = mi*16 + hi*4 + r)
    float v1[16], v2[16];
    int   k1[16];
#pragma unroll
    for (int s = 0; s < 16; ++s) { v1[s] = -FLT_MAX; v2[s] = -FLT_MAX; k1[s] = 0; }

    __syncthreads();   // prologue staging ordered before loop (one-time)

    const int bswz = lo & 7;

    for (int t = 0; t < NTILES; ++t) {
        if (t < NTILES - 1) asm volatile("s_waitcnt vmcnt(8)" ::: "memory");
        else                asm volatile("s_waitcnt vmcnt(0)" ::: "memory");
        __builtin_amdgcn_sched_barrier(0);

        const unsigned short* Bc = (const unsigned short*)((t & 1) ? b1 : b0);
        f32x4 acc[4];
#pragma unroll
        for (int mi = 0; mi < 4; ++mi) acc[mi] = (f32x4){0.f, 0.f, 0.f, 0.f};
#pragma unroll
        for (int ks = 0; ks < 8; ++ks) {
            short8 bf = *(const short8*)&Bc[lo * 256 + (((ks * 4 + hi) ^ bswz)) * 8];
#pragma unroll
            for (int mi = 0; mi < 4; ++mi)
                acc[mi] = __builtin_amdgcn_mfma_f32_16x16x32_bf16(af[mi][ks], bf, acc[mi], 0, 0, 0);
        }

        const int kv = t * BN + wid * 16 + lo;
#pragma unroll
        for (int mi = 0; mi < 4; ++mi)
#pragma unroll
            for (int r = 0; r < 4; ++r) {
                int s = mi * 4 + r;
                float v = acc[mi][r];
                v2[s] = fmaxf(v2[s], fminf(v1[s], v));    // streaming 2nd max
                k1[s] = (v > v1[s]) ? kv : k1[s];
                v1[s] = fmaxf(v1[s], v);
            }

        if (t + 2 < NTILES) {
            // ds_reads of this tile complete before overwriting the buffer
            asm volatile("s_waitcnt lgkmcnt(0)" ::: "memory");
            __builtin_amdgcn_sched_barrier(0);
            stage(t + 2, (t & 1) ? b1 : b0);
        }
    }

    // ---- loop done: vmcnt drained (last iter waits vmcnt(0)); LDS reusable ----
    __syncthreads();                       // all waves finished with Bw region
    if (tid < BM) { cnt[tid] = 0; rowmaxKey[tid] = 0u; }
    __syncthreads();                       // aux init visible

    // ---- exact bf16 row max: reduce v1 over 16 lo-lanes, cross-wave via LDS ----
#pragma unroll
    for (int s = 0; s < 16; ++s) {
        float w = v1[s];
        w = fmaxf(w, __shfl_xor(w, 1));
        w = fmaxf(w, __shfl_xor(w, 2));
        w = fmaxf(w, __shfl_xor(w, 4));
        w = fmaxf(w, __shfl_xor(w, 8));
        if (lo == 0) {
            int row = (s >> 2) * 16 + hi * 4 + (s & 3);
            atomicMax(&rowmaxKey[row], fkey(w));
        }
    }
    __syncthreads();

    // ---- emit candidates + flag entries ----
#pragma unroll
    for (int s = 0; s < 16; ++s) {
        int row = (s >> 2) * 16 + hi * 4 + (s & 3);
        float thr = fkey_inv(rowmaxKey[row]) - DELTA;
        if (v1[s] >= thr) {
            int pos = atomicAdd(&cnt[row], 1);
            if (pos < CAP) list[row * CAP + pos] = k1[s];
        }
        if (v2[s] >= thr) {
            int pos = atomicAdd(&cnt[row], 1);
            if (pos < CAP) list[row * CAP + pos] = FLAGBIT | (wid * 16 + lo);
        }
    }
    __syncthreads();

    if (tid < BM) {
        int c = cnt[tid];
        cand_cnt[m0 + tid] = (unsigned char)(c > CAP ? 255 : c);
        int n = c < CAP ? c : CAP;
        for (int j = 0; j < n; ++j) cand_k[(size_t)(m0 + tid) * CAP + j] = list[tid * CAP + j];
    }
}

// ---------------- kernel 3: rescore (incl. stream rescans) + outputs ----------------
__global__ __launch_bounds__(256) void k_final(
    const float* __restrict__ z,
    const float* __restrict__ E,
    const float* __restrict__ En,
    const unsigned char* __restrict__ cand_cnt,
    const int* __restrict__ cand_k,
    float* __restrict__ out,
    float* __restrict__ rowloss) {

    __shared__ float zl[4][256];
    int wid  = threadIdx.x >> 6;
    int lane = threadIdx.x & 63;
    int m    = blockIdx.x * 4 + wid;

    const float* zr = z + (size_t)m * DDIM;
    const float4 zz = *(const float4*)&zr[lane * 4];
    *(float4*)&zl[wid][lane * 4] = zz;          // full z row for stream rescans
    asm volatile("s_waitcnt lgkmcnt(0)" ::: "memory");

    float bv = -FLT_MAX;
    int   bk = 0x7fffffff;

    // rescan one column-stream (codes k ≡ cb mod 64), 2 codes/lane, exact fp32
    auto rescan = [&](int cb) {
#pragma unroll
        for (int j = 0; j < 2; ++j) {
            int k = cb + (lane * 2 + j) * 64;
            const float4* er = (const float4*)&En[(size_t)k * DDIM];
            float s0 = 0.f, s1 = 0.f, s2 = 0.f, s3 = 0.f;
#pragma unroll 16
            for (int d4 = 0; d4 < 64; ++d4) {
                float4 e  = er[d4];
                float4 zd = *(const float4*)&zl[wid][d4 * 4];
                s0 += zd.x * e.x; s1 += zd.y * e.y;
                s2 += zd.z * e.z; s3 += zd.w * e.w;
            }
            float s = (s0 + s1) + (s2 + s3);
            if (s > bv || (s == bv && k < bk)) { bv = s; bk = k; }
        }
    };

    int c = cand_cnt[m];
    if (c != 255) {
        for (int j = 0; j < c; ++j) {
            int e = cand_k[(size_t)m * CAP + j];
            if (e < FLAGBIT) {
                const float4 ee = *(const float4*)&En[(size_t)e * DDIM + lane * 4];
                float s = zz.x * ee.x + zz.y * ee.y + zz.z * ee.z + zz.w * ee.w;
#pragma unroll
                for (int off = 1; off < 64; off <<= 1) s += __shfl_xor(s, off);
                if (s > bv || (s == bv && e < bk)) { bv = s; bk = e; }
            } else {
                rescan(e & 63);
            }
        }
    } else {
        for (int cb = 0; cb < 64; ++cb) rescan(cb);   // overflow: full exact scan
    }
    // final argmax reduce across lanes (value, min-k tie)
#pragma unroll
    for (int off = 1; off < 64; off <<= 1) {
        float ov = __shfl_xor(bv, off);
        int   ok = __shfl_xor(bk, off);
        if (ov > bv || (ov == bv && ok < bk)) { bv = ov; bk = ok; }
    }
    const int idx = bk;

    // ---- gather + straight-through + per-row loss ----
    const float* er = E + (size_t)idx * DDIM;
    float zv[4], ev[4];
    float sz = 0.f, se = 0.f;
#pragma unroll
    for (int p = 0; p < 4; ++p) {
        zv[p] = zr[lane + 64 * p]; sz += zv[p] * zv[p];
        ev[p] = er[lane + 64 * p]; se += ev[p] * ev[p];
    }
#pragma unroll
    for (int off = 32; off >= 1; off >>= 1) {
        sz += __shfl_xor(sz, off);
        se += __shfl_xor(se, off);
    }
    float nz = fmaxf(sqrtf(sz), 1e-8f);
    float ne = fmaxf(sqrtf(se), 1e-8f);

    float rs = 0.f;
    float* zq = out + 1 + (size_t)m * DDIM;
#pragma unroll
    for (int p = 0; p < 4; ++p) {
        float zn = zv[p] / nz;
        float en = ev[p] / ne;
        float d  = en - zn;
        rs += d * d;
        zq[lane + 64 * p] = zv[p] + (ev[p] - zv[p]);
    }
#pragma unroll
    for (int off = 32; off >= 1; off >>= 1) rs += __shfl_xor(rs, off);

    if (lane == 0) {
        rowloss[m] = rs;
        out[1 + (size_t)M_ROWS * DDIM + m] = (float)idx;
    }
}

// ---------------- kernel 4: deterministic loss reduction ----------------
__global__ __launch_bounds__(256) void k_loss(const float* __restrict__ rowloss,
                                              float* __restrict__ out) {
    __shared__ double sm[256];
    double s = 0.0;
    for (int i = threadIdx.x; i < M_ROWS; i += 256) s += (double)rowloss[i];
    sm[threadIdx.x] = s;
    __syncthreads();
    for (int st = 128; st > 0; st >>= 1) {
        if (threadIdx.x < st) sm[threadIdx.x] += sm[threadIdx.x + st];
        __syncthreads();
    }
    if (threadIdx.x == 0) {
        float c = (float)(sm[0] / (double)((size_t)M_ROWS * DDIM));
        out[0] = c + 0.05f * c;
    }
}

extern "C" void kernel_launch(void* const* d_in, const int* in_sizes, int n_in,
                              void* d_out, int out_size, void* d_ws, size_t ws_size,
                              hipStream_t stream) {
    const float* z = (const float*)d_in[0];
    const float* E = (const float*)d_in[1];
    float* out = (float*)d_out;

    char* ws = (char*)d_ws;
    size_t off = 0;
    float*          En       = (float*)(ws + off);          off += (size_t)K_CODES * DDIM * 4;  // 8 MB
    unsigned short* En_b     = (unsigned short*)(ws + off); off += (size_t)K_CODES * DDIM * 2;  // 4 MB
    int*            cand_k   = (int*)(ws + off);            off += (size_t)M_ROWS * CAP * 4;    // 2 MB
    unsigned char*  cand_cnt = (unsigned char*)(ws + off);  off += (size_t)M_ROWS;              // 32 KB
    float*          rowloss  = (float*)(ws + off);

    k_norm_E<<<K_CODES / 4, 256, 0, stream>>>(E, En, En_b);
    k_cand<<<M_ROWS / BM, 256, 0, stream>>>(z, En_b, cand_cnt, cand_k);
    k_final<<<M_ROWS / 4, 256, 0, stream>>>(z, E, En, cand_cnt, cand_k, out, rowloss);
    k_loss<<<1, 256, 0, stream>>>(rowloss, out);
}